// Round 7
// baseline (81.854 us; speedup 1.0000x reference)
//
#include <hip/hip_runtime.h>

#define NPTS 4096
#define N0V  10242
#define EPSV 1e-5f
#define NBLK 256
#define SLOTS 16

__device__ __forceinline__ float fmul(float a,float b){return __fmul_rn(a,b);}
__device__ __forceinline__ float fadd(float a,float b){return __fadd_rn(a,b);}
__device__ __forceinline__ float fsub(float a,float b){return __fsub_rn(a,b);}

// ---------------- prep: pack W^T, pack vertex{x,y,z,v2}, zero acc slots/counters ----------------
__global__ __launch_bounds__(256) void k_init(
    const float* __restrict__ W0, const float* __restrict__ W1, const float* __restrict__ W2,
    const float* __restrict__ vertex,
    float* __restrict__ wt0, float* __restrict__ wt1, float* __restrict__ wt2,
    float* __restrict__ vpk, float* __restrict__ accg, int* __restrict__ cnt)
{
  int t = blockIdx.x * 256 + threadIdx.x;
  if (t < 5120) {                                  // wt0: [40][128] float4 (K=147 zero-padded)
    int c4 = t >> 7, o = t & 127;
    float4 v; float* vv = (float*)&v;
    #pragma unroll
    for (int j = 0; j < 4; j++) { int c = c4*4 + j; vv[j] = (c < 147) ? W0[o*147 + c] : 0.0f; }
    ((float4*)wt0)[t] = v;
  } else if (t < 9216) {                           // wt1: [32][128] float4
    int u = t - 5120; int c4 = u >> 7, o = u & 127;
    float4 v; float* vv = (float*)&v;
    #pragma unroll
    for (int j = 0; j < 4; j++) vv[j] = W1[o*128 + c4*4 + j];
    ((float4*)wt1)[u] = v;
  } else if (t < 13312) {                          // wt2
    int u = t - 9216; int c4 = u >> 7, o = u & 127;
    float4 v; float* vv = (float*)&v;
    #pragma unroll
    for (int j = 0; j < 4; j++) vv[j] = W2[o*128 + c4*4 + j];
    ((float4*)wt2)[u] = v;
  } else if (t < 16384) {                          // zero 3*16*256 floats + counters
    int u = t - 13312;
    ((float4*)accg)[u] = make_float4(0.f,0.f,0.f,0.f);
    if (u < 4) cnt[u] = 0;
  } else if (t < 16384 + N0V) {                    // vpk[m] = {x,y,z,|v|^2}
    int m = t - 16384;
    float x = vertex[3*m], y = vertex[3*m+1], z = vertex[3*m+2];
    float v2 = fadd(fadd(fmul(x,x),fmul(y,y)),fmul(z,z));
    ((float4*)vpk)[m] = make_float4(x,y,z,v2);
  }
}

struct Params {
  const float* orig; const float* proj; const float* vertex; const int* nidx;
  const float* wt0; const float* wt1; const float* wt2; const float* vpk;
  const float* b0; const float* g0; const float* be0;
  const float* b1; const float* g1; const float* be1;
  const float* b2; const float* g2; const float* be2;
  float* accg; int* cnt; float* out;
};

// async DMA: stage nchunks x 1KB of packed weights global->LDS (linear both sides).
// LDS dest per instr is wave-uniform base + lane*16; global src is per-lane.
__device__ __forceinline__ void stage_w(const float* __restrict__ src, float* dst,
                                        int nchunks, int w, int lane)
{
  for (int i = w; i < nchunks; i += 16){
    const float* g = src + (size_t)(i*64 + lane)*4;
    float* l = dst + (size_t)i*256;                 // wave-uniform LDS base
    __builtin_amdgcn_global_load_lds(
        (const __attribute__((address_space(1))) void*)g,
        (__attribute__((address_space(3))) void*)l,
        16, 0, 0);
  }
}

// dot-product core: thread = (o, rgrp 0..7); 4 rows each; x broadcast from LDS, W per-lane from LDS
template<int K4>
__device__ __forceinline__ void mm_compute(const float4* xs4, int xstr4,
                                           const float4* wlds,
                                           const float* __restrict__ bias,
                                           int o, int rgrp, float* acc)
{
  #pragma unroll
  for (int r=0;r<4;r++) acc[r]=0.0f;
  const float4* wp = wlds + o;
  const float4* xb = xs4 + rgrp*4*xstr4;
  #pragma unroll
  for (int c4=0;c4<K4;c4++){
    float4 wv = wp[c4*128];
    #pragma unroll
    for (int r=0;r<4;r++){
      float4 xv = xb[r*xstr4 + c4];
      acc[r]=fmaf(xv.x,wv.x,acc[r]);
      acc[r]=fmaf(xv.y,wv.y,acc[r]);
      acc[r]=fmaf(xv.z,wv.z,acc[r]);
      acc[r]=fmaf(xv.w,wv.w,acc[r]);
    }
  }
  float bo = bias[o];
  #pragma unroll
  for (int r=0;r<4;r++) acc[r] += bo;
}

// partials -> global atomic slots -> counter barrier -> redundant small stats -> stS/stB in LDS.
// Next layer's weight staging is issued right after the first syncthreads (hides under the spin).
__device__ __forceinline__ void layer_stats(const float* acc4,
    float* __restrict__ accL, int* __restrict__ cntp,
    const float* __restrict__ g, const float* __restrict__ be,
    const float* __restrict__ stage_src, float* stage_dst, int stage_chunks,
    float* redp, float* red2, float* stS, float* stB, int t, int blk)
{
  float s1=0.0f, s2=0.0f;
  #pragma unroll
  for (int r=0;r<4;r++){ s1 += acc4[r]; s2 = fmaf(acc4[r],acc4[r],s2); }
  int o = t & 127, rgrp = t >> 7;
  redp[rgrp*128 + o]        = s1;
  redp[1024 + rgrp*128 + o] = s2;
  __syncthreads();                                  // all waves done with mm (and LDS weights)
  if (stage_src) stage_w(stage_src, stage_dst, stage_chunks, t >> 6, t & 63);
  if (t < 256){
    int q = t >> 7, ch = t & 127;
    const float* rp = redp + q*1024 + ch;
    float v = ((rp[0]+rp[128])+(rp[256]+rp[384])) + ((rp[512]+rp[640])+(rp[768]+rp[896]));
    atomicAdd(&accL[(blk & (SLOTS-1))*256 + t], v); // device-scope, coherent point
  }
  __syncthreads();   // vmcnt(0): this block's atomics globally performed
  if (t == 0){
    __hip_atomic_fetch_add(cntp, 1, __ATOMIC_RELEASE, __HIP_MEMORY_SCOPE_AGENT);
    while (__hip_atomic_load(cntp, __ATOMIC_ACQUIRE, __HIP_MEMORY_SCOPE_AGENT) < NBLK)
      __builtin_amdgcn_s_sleep(2);
  }
  __syncthreads();
  if (t < 256){
    float v = 0.0f;
    #pragma unroll
    for (int s=0;s<SLOTS;s++)
      v += __hip_atomic_load(&accL[s*256 + t], __ATOMIC_RELAXED, __HIP_MEMORY_SCOPE_AGENT);
    red2[t] = v;
  }
  __syncthreads();
  if (t < 128){
    float S = red2[t], Q = red2[128 + t];
    float mean = S * (1.0f/8192.0f);
    float var  = Q * (1.0f/8192.0f) - mean*mean;
    float inv  = 1.0f / __fsqrt_rn(var + EPSV);
    float sc = g[t]*inv;
    stS[t] = sc;
    stB[t] = be[t] - mean*sc;
  }
  __syncthreads();                                  // also drains staging vmcnt per wave
}

// in-place affine+relu on [32][132] tile (f4 stride 33, cols 0..127); 1024 threads, 1 f4 each
__device__ __forceinline__ void transform_buf(float* buf, const float* stS, const float* stB, int t)
{
  float4* b4 = (float4*)buf;
  int r = t >> 5, c4 = t & 31;
  float4 v = b4[r*33 + c4];
  int c = c4*4;
  v.x = fmaxf(fmaf(v.x, stS[c  ], stB[c  ]), 0.0f);
  v.y = fmaxf(fmaf(v.y, stS[c+1], stB[c+1]), 0.0f);
  v.z = fmaxf(fmaf(v.z, stS[c+2], stB[c+2]), 0.0f);
  v.w = fmaxf(fmaf(v.w, stS[c+3], stB[c+3]), 0.0f);
  b4[r*33 + c4] = v;
  __syncthreads();
}

__global__ __launch_bounds__(1024) void k_fused(Params p)
{
  extern __shared__ __align__(16) float ldsw[];  // 5120 float4 = 80KB weight buffer
  __shared__ __align__(16) float bufA[32*160];   // x0 [32][160]; later y1/x2 [32][132]
  __shared__ __align__(16) float bufB[32*132];   // y0/x1; later y2
  __shared__ float redp[2048];
  __shared__ float red2[256];
  __shared__ float stS[128];
  __shared__ float stB[128];

  const int t    = threadIdx.x;
  const int blk  = blockIdx.x;
  const int lane = t & 63;
  const int w    = t >> 6;            // wave 0..15
  const int b    = blk >> 7;
  const int n0   = (blk & 127) * 32;
  const int o    = t & 127;
  const int rgrp = t >> 7;            // 0..7 -> rows rgrp*4 .. +3

  // kick off wt0 staging immediately; completes under the feat scan
  stage_w(p.wt0, ldsw, 80, w, lane);

  // ---------------- feat: block's 32 rows -> bufA[row][0..159]; 2 rows per wave ----------------
  {
    float v0x=p.vertex[0], v0y=p.vertex[1], v0z=p.vertex[2];
    float r  = __fsqrt_rn(fadd(fadd(fmul(v0x,v0x),fmul(v0y,v0y)),fmul(v0z,v0z)));
    float rr = fmul(r,r);
    int j0 = p.nidx[0];
    float ax=p.vertex[3*j0], ay=p.vertex[3*j0+1], az=p.vertex[3*j0+2];
    float dx=fsub(v0x,ax), dy=fsub(v0y,ay), dz=fsub(v0z,az);
    float t2 = fadd(fadd(fmul(dx,dx),fmul(dy,dy)),fmul(dz,dz));
    const float4* vp4 = (const float4*)p.vpk;

    int firsts[2]; int hass[2];
    #pragma unroll
    for (int rr_i=0; rr_i<2; rr_i++){
      const int row = w*2 + rr_i;
      const int n = n0 + row;
      const float* ob = p.orig + (b*19)*NPTS + n;
      float x=ob[0], y=ob[NPTS], z=ob[2*NPTS];
      float nrm = __fsqrt_rn(fadd(fadd(fmul(x,x),fmul(y,y)),fmul(z,z)));
      float s = __fdiv_rn(r,nrm);
      float px=fmul(x,s), py=fmul(y,s), pz=fmul(z,s);
      int first=0, has=0;
      for (int c0=0; c0<N0V; c0+=256){           // 4 chunks in flight per iteration
        int m0=c0+lane, m1=m0+64, m2=m0+128, m3=m0+192;
        float4 va = vp4[min(m0, N0V-1)];
        float4 vb = vp4[min(m1, N0V-1)];
        float4 vc = vp4[min(m2, N0V-1)];
        float4 vd = vp4[min(m3, N0V-1)];
        float dta = fadd(fadd(fmul(px,va.x),fmul(py,va.y)),fmul(pz,va.z));
        float dtb = fadd(fadd(fmul(px,vb.x),fmul(py,vb.y)),fmul(pz,vb.z));
        float dtc = fadd(fadd(fmul(px,vc.x),fmul(py,vc.y)),fmul(pz,vc.z));
        float dtd = fadd(fadd(fmul(px,vd.x),fmul(py,vd.y)),fmul(pz,vd.z));
        bool h0 = (m0<N0V) && (fsub(fadd(rr,va.w),fmul(2.0f,dta)) <= t2);
        bool h1 = (m1<N0V) && (fsub(fadd(rr,vb.w),fmul(2.0f,dtb)) <= t2);
        bool h2 = (m2<N0V) && (fsub(fadd(rr,vc.w),fmul(2.0f,dtc)) <= t2);
        bool h3 = (m3<N0V) && (fsub(fadd(rr,vd.w),fmul(2.0f,dtd)) <= t2);
        unsigned long long bal;
        if ((bal=__ballot(h0))){ first=c0     +__builtin_ctzll(bal); has=1; break; }
        if ((bal=__ballot(h1))){ first=c0+ 64+__builtin_ctzll(bal); has=1; break; }
        if ((bal=__ballot(h2))){ first=c0+128+__builtin_ctzll(bal); has=1; break; }
        if ((bal=__ballot(h3))){ first=c0+192+__builtin_ctzll(bal); has=1; break; }
      }
      firsts[rr_i]=first; hass[rr_i]=has;
    }
    const float* pb = p.proj + (long)b*128*N0V;
    #pragma unroll
    for (int rr_i=0; rr_i<2; rr_i++){
      const int row = w*2 + rr_i;
      const int n = n0 + row;
      #pragma unroll
      for (int k=0;k<3;k++){
        int idx = lane + k*64;
        if (idx < 160){
          float v;
          if (idx < 19)        v = p.orig[(b*19+idx)*NPTS + n];
          else if (idx < 147)  v = hass[rr_i] ? pb[(long)(idx-19)*N0V + firsts[rr_i]] : 0.0f;
          else                 v = 0.0f;
          bufA[row*160 + idx] = v;
        }
      }
    }
  }
  __syncthreads();   // feat done AND wt0 staging drained (vmcnt(0) at barrier)

  float acc[4];

  // ---------------- layer 0 ----------------
  mm_compute<40>((const float4*)bufA, 40, (const float4*)ldsw, p.b0, o, rgrp, acc);
  #pragma unroll
  for (int r=0;r<4;r++) bufB[(rgrp*4+r)*132 + o] = acc[r];
  layer_stats(acc, p.accg,        p.cnt,   p.g0, p.be0, p.wt1, ldsw, 64,
              redp, red2, stS, stB, t, blk);
  transform_buf(bufB, stS, stB, t);

  // ---------------- layer 1 ----------------
  mm_compute<32>((const float4*)bufB, 33, (const float4*)ldsw, p.b1, o, rgrp, acc);
  #pragma unroll
  for (int r=0;r<4;r++) bufA[(rgrp*4+r)*132 + o] = acc[r];
  layer_stats(acc, p.accg + 4096, p.cnt+1, p.g1, p.be1, p.wt2, ldsw, 64,
              redp, red2, stS, stB, t, blk);
  transform_buf(bufA, stS, stB, t);

  // ---------------- layer 2 ----------------
  mm_compute<32>((const float4*)bufA, 33, (const float4*)ldsw, p.b2, o, rgrp, acc);
  layer_stats(acc, p.accg + 8192, p.cnt+2, p.g2, p.be2, nullptr, nullptr, 0,
              redp, red2, stS, stB, t, blk);

  // affine+relu in regs -> LDS -> coalesced transposed store
  {
    float ss = stS[o], sb = stB[o];
    #pragma unroll
    for (int r=0;r<4;r++)
      bufB[(rgrp*4+r)*132 + o] = fmaxf(fmaf(acc[r], ss, sb), 0.0f);
  }
  __syncthreads();
  {
    float* ob = p.out + (long)b*128*NPTS + n0;
    int oo = t >> 3, j = (t & 7) * 4;            // 128 outputs x 32 rows, 1 float4/thread
    float4 v;
    v.x = bufB[(j  )*132 + oo];
    v.y = bufB[(j+1)*132 + oo];
    v.z = bufB[(j+2)*132 + oo];
    v.w = bufB[(j+3)*132 + oo];
    *(float4*)(ob + (long)oo*NPTS + j) = v;
  }
}

extern "C" void kernel_launch(void* const* d_in, const int* in_sizes, int n_in,
                              void* d_out, int out_size, void* d_ws, size_t ws_size,
                              hipStream_t stream)
{
  const float* orig   = (const float*)d_in[0];
  const float* proj   = (const float*)d_in[1];
  const float* vertex = (const float*)d_in[2];
  const int*   nidx   = (const int*)d_in[3];
  const float* W0 = (const float*)d_in[4];
  const float* b0 = (const float*)d_in[5];
  const float* g0 = (const float*)d_in[6];
  const float* be0= (const float*)d_in[7];
  const float* W1 = (const float*)d_in[8];
  const float* b1 = (const float*)d_in[9];
  const float* g1 = (const float*)d_in[10];
  const float* be1= (const float*)d_in[11];
  const float* W2 = (const float*)d_in[12];
  const float* b2 = (const float*)d_in[13];
  const float* g2 = (const float*)d_in[14];
  const float* be2= (const float*)d_in[15];
  float* out = (float*)d_out;

  float* ws   = (float*)d_ws;
  float* accg = ws;                         // 3*16*256 = 12288 floats
  int*   cnt  = (int*)(ws + 12288);         // 4 ints (pad to 16)
  float* wt0  = ws + 12304;                 // 5120 float4 = 20480 floats
  float* wt1  = wt0 + 20480;                // 16384
  float* wt2  = wt1 + 16384;                // 16384
  float* vpk  = wt2 + 16384;                // 10242 float4 = 40968 floats

  static int attr_set = 0;
  if (!attr_set) {
    hipFuncSetAttribute((const void*)k_fused,
                        hipFuncAttributeMaxDynamicSharedMemorySize, 81920);
    attr_set = 1;
  }

  k_init<<<105, 256, 0, stream>>>(W0, W1, W2, vertex, wt0, wt1, wt2, vpk, accg, cnt);

  Params p{orig, proj, vertex, nidx, wt0, wt1, wt2, vpk,
           b0, g0, be0, b1, g1, be1, b2, g2, be2,
           accg, cnt, out};
  void* args[] = {(void*)&p};
  hipLaunchCooperativeKernel((const void*)k_fused, dim3(NBLK), dim3(1024), args, 81920, stream);
}

// Round 8
// 69.286 us; speedup vs baseline: 1.1814x; 1.1814x over previous
//
#include <hip/hip_runtime.h>

#define NPTS 4096
#define N0V  10242
#define EPSV 1e-5f
#define NBLK 256
#define SLOTS 16

__device__ __forceinline__ float fmul(float a,float b){return __fmul_rn(a,b);}
__device__ __forceinline__ float fadd(float a,float b){return __fadd_rn(a,b);}
__device__ __forceinline__ float fsub(float a,float b){return __fsub_rn(a,b);}

// ---------------- prep: pack W^T, pack vertex{x,y,z,v2}, zero acc slots/counters ----------------
__global__ __launch_bounds__(256) void k_init(
    const float* __restrict__ W0, const float* __restrict__ W1, const float* __restrict__ W2,
    const float* __restrict__ vertex,
    float* __restrict__ wt0, float* __restrict__ wt1, float* __restrict__ wt2,
    float* __restrict__ vpk, float* __restrict__ accg, int* __restrict__ cnt)
{
  int t = blockIdx.x * 256 + threadIdx.x;
  if (t < 5120) {                                  // wt0: [40][128] float4 (K=147 zero-padded)
    int c4 = t >> 7, o = t & 127;
    float4 v; float* vv = (float*)&v;
    #pragma unroll
    for (int j = 0; j < 4; j++) { int c = c4*4 + j; vv[j] = (c < 147) ? W0[o*147 + c] : 0.0f; }
    ((float4*)wt0)[t] = v;
  } else if (t < 9216) {                           // wt1: [32][128] float4
    int u = t - 5120; int c4 = u >> 7, o = u & 127;
    float4 v; float* vv = (float*)&v;
    #pragma unroll
    for (int j = 0; j < 4; j++) vv[j] = W1[o*128 + c4*4 + j];
    ((float4*)wt1)[u] = v;
  } else if (t < 13312) {                          // wt2
    int u = t - 9216; int c4 = u >> 7, o = u & 127;
    float4 v; float* vv = (float*)&v;
    #pragma unroll
    for (int j = 0; j < 4; j++) vv[j] = W2[o*128 + c4*4 + j];
    ((float4*)wt2)[u] = v;
  } else if (t < 16384) {                          // zero 3*16*256 floats + counters
    int u = t - 13312;
    ((float4*)accg)[u] = make_float4(0.f,0.f,0.f,0.f);
    if (u < 4) cnt[u] = 0;
  } else if (t < 16384 + N0V) {                    // vpk[m] = {x,y,z,|v|^2}
    int m = t - 16384;
    float x = vertex[3*m], y = vertex[3*m+1], z = vertex[3*m+2];
    float v2 = fadd(fadd(fmul(x,x),fmul(y,y)),fmul(z,z));
    ((float4*)vpk)[m] = make_float4(x,y,z,v2);
  }
}

struct Params {
  const float* orig; const float* proj; const float* vertex; const int* nidx;
  const float* wt0; const float* wt1; const float* wt2; const float* vpk;
  const float* b0; const float* g0; const float* be0;
  const float* b1; const float* g1; const float* be1;
  const float* b2; const float* g2; const float* be2;
  float* accg; int* cnt; float* out;
};

// async DMA: stage nchunks x 1KB of packed weights global->LDS (linear both sides).
__device__ __forceinline__ void stage_w(const float* __restrict__ src, float* dst,
                                        int nchunks, int w, int lane)
{
  for (int i = w; i < nchunks; i += 16){
    const float* g = src + (size_t)(i*64 + lane)*4;
    float* l = dst + (size_t)i*256;                 // wave-uniform LDS base
    __builtin_amdgcn_global_load_lds(
        (const __attribute__((address_space(1))) void*)g,
        (__attribute__((address_space(3))) void*)l,
        16, 0, 0);
  }
}

// dot-product core: thread = (o, rgrp 0..7); 4 rows each; x broadcast from LDS, W per-lane from LDS
template<int K4>
__device__ __forceinline__ void mm_compute(const float4* xs4, int xstr4,
                                           const float4* wlds,
                                           const float* __restrict__ bias,
                                           int o, int rgrp, float* acc)
{
  #pragma unroll
  for (int r=0;r<4;r++) acc[r]=0.0f;
  const float4* wp = wlds + o;
  const float4* xb = xs4 + rgrp*4*xstr4;
  #pragma unroll
  for (int c4=0;c4<K4;c4++){
    float4 wv = wp[c4*128];
    #pragma unroll
    for (int r=0;r<4;r++){
      float4 xv = xb[r*xstr4 + c4];
      acc[r]=fmaf(xv.x,wv.x,acc[r]);
      acc[r]=fmaf(xv.y,wv.y,acc[r]);
      acc[r]=fmaf(xv.z,wv.z,acc[r]);
      acc[r]=fmaf(xv.w,wv.w,acc[r]);
    }
  }
  float bo = bias[o];
  #pragma unroll
  for (int r=0;r<4;r++) acc[r] += bo;
}

// partials -> global atomic slots -> RELAXED counter barrier (no acquire/release: no L2
// invalidate/writeback storms on multi-XCD) -> redundant small stats -> stS/stB in LDS.
// Correctness: (1) arrival: __syncthreads drains vmcnt => this block's slot atomicAdds are
// globally performed before the relaxed increment issues; (2) readers: slot loads are
// control-dependent on observing cnt==NBLK, and all ops meet at the coherence point via
// scope flags (freshness is from scope, not ordering).
__device__ __forceinline__ void layer_stats(const float* acc4,
    float* __restrict__ accL, int* __restrict__ cntp,
    const float* __restrict__ g, const float* __restrict__ be,
    const float* __restrict__ stage_src, float* stage_dst, int stage_chunks,
    float* redp, float* red2, float* stS, float* stB, int t, int blk)
{
  float s1=0.0f, s2=0.0f;
  #pragma unroll
  for (int r=0;r<4;r++){ s1 += acc4[r]; s2 = fmaf(acc4[r],acc4[r],s2); }
  int o = t & 127, rgrp = t >> 7;
  redp[rgrp*128 + o]        = s1;
  redp[1024 + rgrp*128 + o] = s2;
  __syncthreads();                                  // all waves done with mm (and LDS weights)
  if (stage_src) stage_w(stage_src, stage_dst, stage_chunks, t >> 6, t & 63);
  if (t < 256){
    int q = t >> 7, ch = t & 127;
    const float* rp = redp + q*1024 + ch;
    float v = ((rp[0]+rp[128])+(rp[256]+rp[384])) + ((rp[512]+rp[640])+(rp[768]+rp[896]));
    atomicAdd(&accL[(blk & (SLOTS-1))*256 + t], v); // agent-scope, coherence point
  }
  __syncthreads();   // vmcnt(0): this block's atomics globally performed
  if (t == 0){
    __hip_atomic_fetch_add(cntp, 1, __ATOMIC_RELAXED, __HIP_MEMORY_SCOPE_AGENT);
    while (__hip_atomic_load(cntp, __ATOMIC_RELAXED, __HIP_MEMORY_SCOPE_AGENT) < NBLK)
      __builtin_amdgcn_s_sleep(2);
  }
  __syncthreads();
  if (t < 256){
    float v = 0.0f;
    #pragma unroll
    for (int s=0;s<SLOTS;s++)
      v += __hip_atomic_load(&accL[s*256 + t], __ATOMIC_RELAXED, __HIP_MEMORY_SCOPE_AGENT);
    red2[t] = v;
  }
  __syncthreads();
  if (t < 128){
    float S = red2[t], Q = red2[128 + t];
    float mean = S * (1.0f/8192.0f);
    float var  = Q * (1.0f/8192.0f) - mean*mean;
    float inv  = 1.0f / __fsqrt_rn(var + EPSV);
    float sc = g[t]*inv;
    stS[t] = sc;
    stB[t] = be[t] - mean*sc;
  }
  __syncthreads();                                  // also drains staging vmcnt per wave
}

// in-place affine+relu on [32][132] tile (f4 stride 33, cols 0..127); 1024 threads, 1 f4 each
__device__ __forceinline__ void transform_buf(float* buf, const float* stS, const float* stB, int t)
{
  float4* b4 = (float4*)buf;
  int r = t >> 5, c4 = t & 31;
  float4 v = b4[r*33 + c4];
  int c = c4*4;
  v.x = fmaxf(fmaf(v.x, stS[c  ], stB[c  ]), 0.0f);
  v.y = fmaxf(fmaf(v.y, stS[c+1], stB[c+1]), 0.0f);
  v.z = fmaxf(fmaf(v.z, stS[c+2], stB[c+2]), 0.0f);
  v.w = fmaxf(fmaf(v.w, stS[c+3], stB[c+3]), 0.0f);
  b4[r*33 + c4] = v;
  __syncthreads();
}

__global__ __launch_bounds__(1024) void k_fused(Params p)
{
  extern __shared__ __align__(16) float ldsw[];  // 5120 float4 = 80KB weight buffer
  __shared__ __align__(16) float bufA[32*160];   // x0 [32][160]; later y1/x2 [32][132]
  __shared__ __align__(16) float bufB[32*132];   // y0/x1; later y2
  __shared__ float redp[2048];
  __shared__ float red2[256];
  __shared__ float stS[128];
  __shared__ float stB[128];

  const int t    = threadIdx.x;
  const int blk  = blockIdx.x;
  const int lane = t & 63;
  const int w    = t >> 6;            // wave 0..15
  const int b    = blk >> 7;
  const int n0   = (blk & 127) * 32;
  const int o    = t & 127;
  const int rgrp = t >> 7;            // 0..7 -> rows rgrp*4 .. +3

  // kick off wt0 staging immediately; completes under the feat scan
  stage_w(p.wt0, ldsw, 80, w, lane);

  // ---------------- feat: block's 32 rows -> bufA[row][0..159]; 2 rows per wave ----------------
  {
    float v0x=p.vertex[0], v0y=p.vertex[1], v0z=p.vertex[2];
    float r  = __fsqrt_rn(fadd(fadd(fmul(v0x,v0x),fmul(v0y,v0y)),fmul(v0z,v0z)));
    float rr = fmul(r,r);
    int j0 = p.nidx[0];
    float ax=p.vertex[3*j0], ay=p.vertex[3*j0+1], az=p.vertex[3*j0+2];
    float dx=fsub(v0x,ax), dy=fsub(v0y,ay), dz=fsub(v0z,az);
    float t2 = fadd(fadd(fmul(dx,dx),fmul(dy,dy)),fmul(dz,dz));
    const float4* vp4 = (const float4*)p.vpk;

    int firsts[2]; int hass[2];
    #pragma unroll
    for (int rr_i=0; rr_i<2; rr_i++){
      const int row = w*2 + rr_i;
      const int n = n0 + row;
      const float* ob = p.orig + (b*19)*NPTS + n;
      float x=ob[0], y=ob[NPTS], z=ob[2*NPTS];
      float nrm = __fsqrt_rn(fadd(fadd(fmul(x,x),fmul(y,y)),fmul(z,z)));
      float s = __fdiv_rn(r,nrm);
      float px=fmul(x,s), py=fmul(y,s), pz=fmul(z,s);
      int first=0, has=0;
      for (int c0=0; c0<N0V; c0+=256){           // 4 chunks in flight per iteration
        int m0=c0+lane, m1=m0+64, m2=m0+128, m3=m0+192;
        float4 va = vp4[min(m0, N0V-1)];
        float4 vb = vp4[min(m1, N0V-1)];
        float4 vc = vp4[min(m2, N0V-1)];
        float4 vd = vp4[min(m3, N0V-1)];
        float dta = fadd(fadd(fmul(px,va.x),fmul(py,va.y)),fmul(pz,va.z));
        float dtb = fadd(fadd(fmul(px,vb.x),fmul(py,vb.y)),fmul(pz,vb.z));
        float dtc = fadd(fadd(fmul(px,vc.x),fmul(py,vc.y)),fmul(pz,vc.z));
        float dtd = fadd(fadd(fmul(px,vd.x),fmul(py,vd.y)),fmul(pz,vd.z));
        bool h0 = (m0<N0V) && (fsub(fadd(rr,va.w),fmul(2.0f,dta)) <= t2);
        bool h1 = (m1<N0V) && (fsub(fadd(rr,vb.w),fmul(2.0f,dtb)) <= t2);
        bool h2 = (m2<N0V) && (fsub(fadd(rr,vc.w),fmul(2.0f,dtc)) <= t2);
        bool h3 = (m3<N0V) && (fsub(fadd(rr,vd.w),fmul(2.0f,dtd)) <= t2);
        unsigned long long bal;
        if ((bal=__ballot(h0))){ first=c0     +__builtin_ctzll(bal); has=1; break; }
        if ((bal=__ballot(h1))){ first=c0+ 64+__builtin_ctzll(bal); has=1; break; }
        if ((bal=__ballot(h2))){ first=c0+128+__builtin_ctzll(bal); has=1; break; }
        if ((bal=__ballot(h3))){ first=c0+192+__builtin_ctzll(bal); has=1; break; }
      }
      firsts[rr_i]=first; hass[rr_i]=has;
    }
    const float* pb = p.proj + (long)b*128*N0V;
    #pragma unroll
    for (int rr_i=0; rr_i<2; rr_i++){
      const int row = w*2 + rr_i;
      const int n = n0 + row;
      #pragma unroll
      for (int k=0;k<3;k++){
        int idx = lane + k*64;
        if (idx < 160){
          float v;
          if (idx < 19)        v = p.orig[(b*19+idx)*NPTS + n];
          else if (idx < 147)  v = hass[rr_i] ? pb[(long)(idx-19)*N0V + firsts[rr_i]] : 0.0f;
          else                 v = 0.0f;
          bufA[row*160 + idx] = v;
        }
      }
    }
  }
  __syncthreads();   // feat done AND wt0 staging drained (vmcnt(0) at barrier)

  float acc[4];

  // ---------------- layer 0 ----------------
  mm_compute<40>((const float4*)bufA, 40, (const float4*)ldsw, p.b0, o, rgrp, acc);
  #pragma unroll
  for (int r=0;r<4;r++) bufB[(rgrp*4+r)*132 + o] = acc[r];
  layer_stats(acc, p.accg,        p.cnt,   p.g0, p.be0, p.wt1, ldsw, 64,
              redp, red2, stS, stB, t, blk);
  transform_buf(bufB, stS, stB, t);

  // ---------------- layer 1 ----------------
  mm_compute<32>((const float4*)bufB, 33, (const float4*)ldsw, p.b1, o, rgrp, acc);
  #pragma unroll
  for (int r=0;r<4;r++) bufA[(rgrp*4+r)*132 + o] = acc[r];
  layer_stats(acc, p.accg + 4096, p.cnt+1, p.g1, p.be1, p.wt2, ldsw, 64,
              redp, red2, stS, stB, t, blk);
  transform_buf(bufA, stS, stB, t);

  // ---------------- layer 2 ----------------
  mm_compute<32>((const float4*)bufA, 33, (const float4*)ldsw, p.b2, o, rgrp, acc);
  layer_stats(acc, p.accg + 8192, p.cnt+2, p.g2, p.be2, nullptr, nullptr, 0,
              redp, red2, stS, stB, t, blk);

  // affine+relu in regs -> LDS -> coalesced transposed store
  {
    float ss = stS[o], sb = stB[o];
    #pragma unroll
    for (int r=0;r<4;r++)
      bufB[(rgrp*4+r)*132 + o] = fmaxf(fmaf(acc[r], ss, sb), 0.0f);
  }
  __syncthreads();
  {
    float* ob = p.out + (long)b*128*NPTS + n0;
    int oo = t >> 3, j = (t & 7) * 4;            // 128 outputs x 32 rows, 1 float4/thread
    float4 v;
    v.x = bufB[(j  )*132 + oo];
    v.y = bufB[(j+1)*132 + oo];
    v.z = bufB[(j+2)*132 + oo];
    v.w = bufB[(j+3)*132 + oo];
    *(float4*)(ob + (long)oo*NPTS + j) = v;
  }
}

extern "C" void kernel_launch(void* const* d_in, const int* in_sizes, int n_in,
                              void* d_out, int out_size, void* d_ws, size_t ws_size,
                              hipStream_t stream)
{
  const float* orig   = (const float*)d_in[0];
  const float* proj   = (const float*)d_in[1];
  const float* vertex = (const float*)d_in[2];
  const int*   nidx   = (const int*)d_in[3];
  const float* W0 = (const float*)d_in[4];
  const float* b0 = (const float*)d_in[5];
  const float* g0 = (const float*)d_in[6];
  const float* be0= (const float*)d_in[7];
  const float* W1 = (const float*)d_in[8];
  const float* b1 = (const float*)d_in[9];
  const float* g1 = (const float*)d_in[10];
  const float* be1= (const float*)d_in[11];
  const float* W2 = (const float*)d_in[12];
  const float* b2 = (const float*)d_in[13];
  const float* g2 = (const float*)d_in[14];
  const float* be2= (const float*)d_in[15];
  float* out = (float*)d_out;

  float* ws   = (float*)d_ws;
  float* accg = ws;                         // 3*16*256 = 12288 floats
  int*   cnt  = (int*)(ws + 12288);         // 4 ints (pad to 16)
  float* wt0  = ws + 12304;                 // 5120 float4 = 20480 floats
  float* wt1  = wt0 + 20480;                // 16384
  float* wt2  = wt1 + 16384;                // 16384
  float* vpk  = wt2 + 16384;                // 10242 float4 = 40968 floats

  static int attr_set = 0;
  if (!attr_set) {
    hipFuncSetAttribute((const void*)k_fused,
                        hipFuncAttributeMaxDynamicSharedMemorySize, 81920);
    attr_set = 1;
  }

  k_init<<<105, 256, 0, stream>>>(W0, W1, W2, vertex, wt0, wt1, wt2, vpk, accg, cnt);

  Params p{orig, proj, vertex, nidx, wt0, wt1, wt2, vpk,
           b0, g0, be0, b1, g1, be1, b2, g2, be2,
           accg, cnt, out};
  void* args[] = {(void*)&p};
  hipLaunchCooperativeKernel((const void*)k_fused, dim3(NBLK), dim3(1024), args, 81920, stream);
}